// Round 1
// baseline (392.591 us; speedup 1.0000x reference)
//
#include <hip/hip_runtime.h>

#define HS   1024
#define SEQ  512
#define NBAT 64
#define INSZ 8
#define NM   4
#define DD   12

__device__ __forceinline__ float fast_tanh(float x){
  // 1 - 2/(e^{2x}+1): exact saturation at +/-inf, NaN-propagating
  float e = __expf(2.0f*x);
  return 1.0f - 2.0f/(e+1.0f);
}

__global__ __launch_bounds__(256,1)
void rnn_scan(const float* __restrict__ x,
              const float* __restrict__ eps,
              const float* __restrict__ means,
              const float* __restrict__ tril,
              const float* __restrict__ mw,
              float* __restrict__ out)
{
  const int b    = blockIdx.x;
  const int tid  = threadIdx.x;
  const int wave = tid >> 6;
  const int lane = tid & 63;

  __shared__ float xs[SEQ*INSZ];     // 16 KB: this batch's whole input sequence
  __shared__ float red[2][4][2];     // double-buffered cross-wave reduction slots

  // ---- mixture weights (uniform, redundant per thread) ----
  float w[NM];
  {
    float s = 0.f;
    #pragma unroll
    for (int k=0;k<NM;k++){ w[k] = fmaxf(mw[k], 1e-6f); s += w[k]; }
    float inv = 1.0f/s;
    #pragma unroll
    for (int k=0;k<NM;k++) w[k] *= inv;
  }

  // ---- preprocessing: mixed[h, 0:12] for owned rows i = tid + j*256 ----
  // mixed = sum_k w_k * (means_k + eps_k,h,: @ L_k^T), L = tril(raw,-1) + diag(|diag-1e-12|+1e-12)
  float m0[4],m1[4],n0[4],n1[4],Im[4][8],h[4];
  #pragma unroll
  for (int j=0;j<4;j++){
    const int i = tid + j*256;
    float ep[NM][DD];
    #pragma unroll
    for (int k=0;k<NM;k++)
      #pragma unroll
      for (int d=0;d<DD;d++)
        ep[k][d] = eps[(k*HS + i)*DD + d];
    float mix[DD];
    #pragma unroll
    for (int e=0;e<DD;e++){
      float a = 0.f;
      #pragma unroll
      for (int k=0;k<NM;k++){
        float se = means[k*DD+e];
        for (int d=0; d<e; d++)                       // strict lower triangle
          se += ep[k][d]*tril[(k*DD+e)*DD + d];
        float dg = fabsf(tril[(k*DD+e)*DD + e] - 1e-12f) + 1e-12f;  // diagonal
        se += ep[k][e]*dg;
        a += w[k]*se;
      }
      mix[e] = a;
    }
    m0[j]=mix[0]; m1[j]=mix[1]; n0[j]=mix[2]; n1[j]=mix[3];
    #pragma unroll
    for (int e=0;e<8;e++) Im[j][e]=mix[4+e];
    h[j]=0.f;
  }

  // stage x[b] into LDS (coalesced)
  for (int idx=tid; idx<SEQ*INSZ; idx+=256) xs[idx] = x[b*SEQ*INSZ + idx];
  __syncthreads();

  const float alpha = 0.1f;
  const float oma   = 0.9f;                 // 1 - alpha
  const float scl   = 500.0f/1024.0f;       // BASE_SCALE / HIDDEN_SIZE
  const float as    = alpha*scl;
  float o = 0.f;                            // o[tid] for tid<10: pinv@h coordinate

  for (int t=0;t<SEQ;t++){
    // u_r = sum_i tanh(h_i) * n[i,r]  -- the only global coupling per step
    float u0=0.f, u1=0.f;
    #pragma unroll
    for (int j=0;j<4;j++){
      float th = fast_tanh(h[j]);
      u0 += th*n0[j];
      u1 += th*n1[j];
    }
    #pragma unroll
    for (int off=32; off>=1; off>>=1){
      u0 += __shfl_xor(u0, off, 64);
      u1 += __shfl_xor(u1, off, 64);
    }
    if (lane==0){ red[t&1][wave][0]=u0; red[t&1][wave][1]=u1; }
    __syncthreads();
    u0 = red[t&1][0][0]+red[t&1][1][0]+red[t&1][2][0]+red[t&1][3][0];
    u1 = red[t&1][0][1]+red[t&1][1][1]+red[t&1][2][1]+red[t&1][3][1];

    const float* xt = &xs[t*INSZ];
    #pragma unroll
    for (int j=0;j<4;j++){
      float inj = 0.f;
      #pragma unroll
      for (int e=0;e<INSZ;e++) inj += xt[e]*Im[j][e];
      h[j] = oma*h[j] + as*(m0[j]*u0 + m1[j]*u1) + alpha*inj;
    }

    // out[b,t,:] = pinv(span) @ h_new; since h in col(span) and pinv@span = I_10:
    // o0 <- u0 path, o1 <- u1 path, o[2..9] <- x path (exact algebraic identity)
    if (tid < 10){
      float add = (tid==0) ? scl*u0 : (tid==1) ? scl*u1 : xt[tid-2];
      o = oma*o + alpha*add;
      out[(b*SEQ + t)*10 + tid] = o;
    }
  }
}

extern "C" void kernel_launch(void* const* d_in, const int* in_sizes, int n_in,
                              void* d_out, int out_size, void* d_ws, size_t ws_size,
                              hipStream_t stream) {
  const float* x     = (const float*)d_in[0];  // (64,512,8)
  const float* eps   = (const float*)d_in[1];  // (4,1024,12)
  const float* means = (const float*)d_in[2];  // (4,12)
  const float* tril  = (const float*)d_in[3];  // (4,12,12)
  const float* mw    = (const float*)d_in[4];  // (4,)
  float* out = (float*)d_out;                  // (64,512,10) fp32

  rnn_scan<<<NBAT, 256, 0, stream>>>(x, eps, means, tril, mw, out);
}

// Round 2
// 290.797 us; speedup vs baseline: 1.3501x; 1.3501x over previous
//
#include <hip/hip_runtime.h>

#define HS   1024
#define SEQ  512
#define NBAT 64
#define INSZ 8
#define NM   4
#define DD   12

// DPP-based add: v += dpp_move(v). old=0 so masked/invalid lanes add 0.
#define DPP_ADD(v, ctrl, rmask, bmask) \
  v += __int_as_float(__builtin_amdgcn_update_dpp(0, __float_as_int(v), ctrl, rmask, bmask, true))

// Canonical gfx9 wave64 sum (LLVM AtomicOptimizer sequence). Lane 63 holds the
// full 64-lane total afterwards. Two values interleaved to pipeline latency.
__device__ __forceinline__ void wave64_sum2(float &a, float &b){
  DPP_ADD(a, 0x111, 0xf, 0xf); DPP_ADD(b, 0x111, 0xf, 0xf);  // row_shr:1
  DPP_ADD(a, 0x112, 0xf, 0xf); DPP_ADD(b, 0x112, 0xf, 0xf);  // row_shr:2
  DPP_ADD(a, 0x114, 0xf, 0xe); DPP_ADD(b, 0x114, 0xf, 0xe);  // row_shr:4
  DPP_ADD(a, 0x118, 0xf, 0xc); DPP_ADD(b, 0x118, 0xf, 0xc);  // row_shr:8
  DPP_ADD(a, 0x142, 0xa, 0xf); DPP_ADD(b, 0x142, 0xa, 0xf);  // row_bcast:15
  DPP_ADD(a, 0x143, 0xc, 0xf); DPP_ADD(b, 0x143, 0xc, 0xf);  // row_bcast:31
}

__device__ __forceinline__ float fast_tanh(float x){
  // 1 - 2*rcp(e^{2x}+1): v_exp + v_rcp only (no IEEE divide). Saturates exactly
  // at +/-inf (exp->inf -> rcp->0 -> 1; exp->0 -> rcp(1)=1 -> -1).
  float e = __expf(x + x);
  float r = __builtin_amdgcn_rcpf(e + 1.0f);
  return __builtin_fmaf(-2.0f, r, 1.0f);
}

__global__ __launch_bounds__(256,1)
void rnn_scan(const float* __restrict__ x,
              const float* __restrict__ eps,
              const float* __restrict__ means,
              const float* __restrict__ tril,
              const float* __restrict__ mw,
              float* __restrict__ out)
{
  const int b    = blockIdx.x;
  const int tid  = threadIdx.x;
  const int wave = tid >> 6;
  const int lane = tid & 63;

  __shared__ float  xs[SEQ*INSZ];                 // 16 KB: whole input sequence
  __shared__ float2 red[2][4];                    // double-buffered wave partials
  __shared__ __align__(16) float outb[SEQ*10];    // 20 KB: staged outputs (no
                                                  // per-step global store -> no
                                                  // vmcnt(0) drain at barrier)

  // ---- mixture weights ----
  float w[NM];
  {
    float s = 0.f;
    #pragma unroll
    for (int k=0;k<NM;k++){ w[k] = fmaxf(mw[k], 1e-6f); s += w[k]; }
    float inv = 1.0f/s;
    #pragma unroll
    for (int k=0;k<NM;k++) w[k] *= inv;
  }

  // ---- preprocessing: mixed[i, 0:12] for owned rows i = tid + j*256 ----
  float m0[4],m1[4],n0[4],n1[4],h[4];
  float2 Im2[4][4];
  #pragma unroll
  for (int j=0;j<4;j++){
    const int i = tid + j*256;
    float ep[NM][DD];
    #pragma unroll
    for (int k=0;k<NM;k++)
      #pragma unroll
      for (int d=0;d<DD;d++)
        ep[k][d] = eps[(k*HS + i)*DD + d];
    float mix[DD];
    #pragma unroll
    for (int e=0;e<DD;e++){
      float a = 0.f;
      #pragma unroll
      for (int k=0;k<NM;k++){
        float se = means[k*DD+e];
        for (int d=0; d<e; d++)                       // strict lower triangle
          se += ep[k][d]*tril[(k*DD+e)*DD + d];
        float dg = fabsf(tril[(k*DD+e)*DD + e] - 1e-12f) + 1e-12f;  // diagonal
        se += ep[k][e]*dg;
        a += w[k]*se;
      }
      mix[e] = a;
    }
    m0[j]=mix[0]; m1[j]=mix[1]; n0[j]=mix[2]; n1[j]=mix[3];
    #pragma unroll
    for (int e=0;e<4;e++) Im2[j][e]=make_float2(mix[4+2*e], mix[5+2*e]);
    h[j]=0.f;
  }

  // stage x[b] into LDS (coalesced, one-time)
  for (int idx=tid; idx<SEQ*INSZ; idx+=256) xs[idx] = x[b*SEQ*INSZ + idx];
  __syncthreads();

  const float alpha = 0.1f;
  const float oma   = 0.9f;
  const float scl   = 500.0f/1024.0f;
  const float as    = alpha*scl;
  float o = 0.f;
  const float2* xs2 = (const float2*)xs;

  #pragma unroll 2
  for (int t=0;t<SEQ;t++){
    // u_r = sum_i tanh(h_i)*n[i,r] -- the only global coupling per step
    float u0=0.f, u1=0.f;
    #pragma unroll
    for (int j=0;j<4;j++){
      float th = fast_tanh(h[j]);
      u0 = __builtin_fmaf(th, n0[j], u0);
      u1 = __builtin_fmaf(th, n1[j], u1);
    }
    wave64_sum2(u0, u1);                 // DPP butterfly, lane 63 has totals
    if (lane==63) red[t&1][wave] = make_float2(u0,u1);

    // inj = x_t @ I^T for owned rows -- independent of u, overlaps the barrier
    float inj[4];
    #pragma unroll
    for (int j=0;j<4;j++){
      float2 acc = make_float2(0.f,0.f);
      #pragma unroll
      for (int e=0;e<4;e++){
        float2 xe = xs2[t*4+e];
        acc.x = __builtin_fmaf(xe.x, Im2[j][e].x, acc.x);
        acc.y = __builtin_fmaf(xe.y, Im2[j][e].y, acc.y);
      }
      inj[j] = acc.x + acc.y;
    }

    __syncthreads();
    float2 r0=red[t&1][0], r1=red[t&1][1], r2=red[t&1][2], r3=red[t&1][3];
    float U0 = (r0.x+r1.x)+(r2.x+r3.x);
    float U1 = (r0.y+r1.y)+(r2.y+r3.y);

    #pragma unroll
    for (int j=0;j<4;j++){
      float mu = __builtin_fmaf(m1[j], U1, m0[j]*U0);
      h[j] = __builtin_fmaf(oma, h[j],
             __builtin_fmaf(as, mu, alpha*inj[j]));
    }

    // o_t = pinv(span) @ h_t exactly (h lives in col(span), pinv@span = I_10)
    if (tid < 10){
      float add = (tid==0) ? scl*U0 : (tid==1) ? scl*U1 : xs[t*8 + tid-2];
      o = __builtin_fmaf(oma, o, alpha*add);
      outb[t*10+tid] = o;
    }
  }

  __syncthreads();
  // burst-dump staged outputs, coalesced float4
  const float4* ob4 = (const float4*)outb;
  float4* o4 = (float4*)out + b*(SEQ*10/4);
  for (int idx=tid; idx<SEQ*10/4; idx+=256) o4[idx] = ob4[idx];
}

extern "C" void kernel_launch(void* const* d_in, const int* in_sizes, int n_in,
                              void* d_out, int out_size, void* d_ws, size_t ws_size,
                              hipStream_t stream) {
  const float* x     = (const float*)d_in[0];  // (64,512,8)
  const float* eps   = (const float*)d_in[1];  // (4,1024,12)
  const float* means = (const float*)d_in[2];  // (4,12)
  const float* tril  = (const float*)d_in[3];  // (4,12,12)
  const float* mw    = (const float*)d_in[4];  // (4,)
  float* out = (float*)d_out;                  // (64,512,10) fp32

  rnn_scan<<<NBAT, 256, 0, stream>>>(x, eps, means, tril, mw, out);
}